// Round 6
// baseline (283.648 us; speedup 1.0000x reference)
//
#include <hip/hip_runtime.h>
#include <cstdint>

#define C_     512
#define HW_    784
#define B_     64
#define NPAIR  50176               // B_*HW_
#define BN_EPS 1e-5f

// Workspace layout:
//   [0, 32768)     : wbits   uint32[512][16]  (bit c%32 of word c/32 = 1 iff W[o][c] < 0)
//   [32768, 40960) : params  float4[512]      {A2, C2, slope, bias}
//
// Math folding:
//   scale[o] = mean|W[o,:]| ; S = 512 - 2*P (P = popcount(a^wsign)) ; y = scale*S
//   bn = A*S + B2,  A = gamma*scale*r, B2 = beta - gamma*mean*r
//   t  = bn + x - shift = (-2A)*P + (512A + B2 - shift) + x = A2*P + C2 + x
//   out = max(t,0) + slope*min(t,0) + bias   (branchless RPReLU)
//
// Journal:
//   R1: nontemporal stores -> WRITE 100->238 MB + L3 eviction. Never again.
//   R2: xv[32] reg-cache defeated by remat under 64-VGPR cap (FETCH 127->64 MB,
//       dur only -4%: latency, not traffic). 83.3 us. BEST KNOWN.
//   R3: sw-pipeline flattened by regalloc; L2 thrash. 113 us.
//   R4: asm-pin sank past the barrier with the loads; half occupancy. 97 us.
//   R5: split kernels: VGPR STILL 32 (scheduler always sinks loads to ~8 in
//       flight), binarize added 40 us. 97+40. REVERTED to fused.
//   INVARIANT across R0-R5: VALUBusy 29-39% regardless of global-load
//       structure. The untouched common code is the phase-2 inner loop:
//       4x s_load_dwordx4 (wbits) + s_load (params) per output, ~64 cy VALU
//       per ~150 cy SMEM wait -> ~30% duty. NEW THEORY: the stall is the
//       scalar-load chain on weights/params, not the x loads.
//   R6 (this): stage wbits (32 KB) + params (8 KB) in LDS once per block;
//       inner loop reads become wave-uniform ds_read_b128 (broadcast,
//       conflict-free, compiler pipelines lgkmcnt well). Otherwise identical
//       to R2. Tell: VALUBusy >55 & dur ~50 = theory right; VALUBusy ~33 &
//       dur ~80 = theory dead, pivot to LDS-staging x.

__global__ __launch_bounds__(64) void precompute_kernel(
    const float* __restrict__ W,
    const float* __restrict__ bn_gamma, const float* __restrict__ bn_beta,
    const float* __restrict__ bn_mean,  const float* __restrict__ bn_var,
    const float* __restrict__ pr_slope, const float* __restrict__ pr_shift,
    const float* __restrict__ pr_bias,
    uint32_t* __restrict__ wbits, float4* __restrict__ params)
{
    const int o    = blockIdx.x;
    const int lane = threadIdx.x;
    const float4* wrow4 = (const float4*)(W + (size_t)o * C_);
    const float4 u = wrow4[2 * lane];
    const float4 v = wrow4[2 * lane + 1];

    float s = fabsf(u.x) + fabsf(u.y) + fabsf(u.z) + fabsf(u.w)
            + fabsf(v.x) + fabsf(v.y) + fabsf(v.z) + fabsf(v.w);
    for (int off = 32; off > 0; off >>= 1) s += __shfl_down(s, off, 64);

    uint32_t m8 = (u.x < 0.f ? 1u : 0u)  | (u.y < 0.f ? 2u : 0u)
                | (u.z < 0.f ? 4u : 0u)  | (u.w < 0.f ? 8u : 0u)
                | (v.x < 0.f ? 16u : 0u) | (v.y < 0.f ? 32u : 0u)
                | (v.z < 0.f ? 64u : 0u) | (v.w < 0.f ? 128u : 0u);

    const uint32_t g0 = __shfl(m8, 4 * lane + 0, 64);
    const uint32_t g1 = __shfl(m8, 4 * lane + 1, 64);
    const uint32_t g2 = __shfl(m8, 4 * lane + 2, 64);
    const uint32_t g3 = __shfl(m8, 4 * lane + 3, 64);
    if (lane < 16)
        wbits[o * 16 + lane] = g0 | (g1 << 8) | (g2 << 16) | (g3 << 24);

    if (lane == 0) {
        float scale = s * (1.0f / (float)C_);
        float r  = rsqrtf(bn_var[o] + BN_EPS);
        float A  = bn_gamma[o] * scale * r;
        float A2 = -2.0f * A;
        float C2 = (float)C_ * A + bn_beta[o] - bn_gamma[o] * bn_mean[o] * r
                 - pr_shift[o];
        params[o] = make_float4(A2, C2, pr_slope[o], pr_bias[o]);
    }
}

// Block: (64 lanes) x (16 waves) = 1024 threads; grid = 784 blocks covering
// the 50,176 flattened (b,hw) pairs exactly. Wave jj binarizes channels
// [32jj, 32jj+32) and computes outputs for those same channels.
// LDS: abits 4.4 KB + wbits 32 KB + params 8 KB ~= 45 KB; blocks/CU remains
// 2 (thread-capped at 2048), so occupancy is unchanged vs R2.
__global__ __launch_bounds__(1024, 8) void fused_kernel(
    const float* __restrict__ x, const float* __restrict__ rsign_bias,
    const uint32_t* __restrict__ wbits, const float4* __restrict__ params,
    float* __restrict__ out)
{
    __shared__ uint32_t abits[64 * 17];       // stride 17: 2-way alias (free)
    __shared__ uint32_t wlds[512 * 16];       // weight sign bits, row-major
    __shared__ float4   plds[512];            // folded per-output params

    const int i   = threadIdx.x;                                  // pair lane
    const int jj  = __builtin_amdgcn_readfirstlane(threadIdx.y);  // wave 0..15
    const int tid = jj * 64 + i;                                  // 0..1023

    const uint32_t pair = (uint32_t)blockIdx.x * 64u + (uint32_t)i;
    const uint32_t b    = pair / 784u;          // magic-mul division
    const uint32_t hw   = pair - b * 784u;
    const size_t   base = (size_t)b * (C_ * HW_) + hw;
    const float*   xg   = x + base;

    const int c0 = jj * 32;                                       // wave-uniform

    // ---- Stage issue: wbits (2 uint4/thread) + params (1 float2/thread).
    // Issued first so their latency hides under the phase-1 x burst.
    const uint4* wsrc = (const uint4*)wbits;        // 2048 uint4 total
    const uint4  w0 = wsrc[2 * tid];
    const uint4  w1 = wsrc[2 * tid + 1];
    const float2 pp2 = ((const float2*)params)[tid]; // 1024 float2 total

    // ---- Phase 1: binarize channels [c0, c0+32) -> one bit-word ----
    {
        float v[32];
        #pragma unroll
        for (int t = 0; t < 32; ++t)
            v[t] = xg[(size_t)(c0 + t) * HW_];
        uint32_t m = 0;
        #pragma unroll
        for (int t = 0; t < 32; ++t)
            if (v[t] + rsign_bias[c0 + t] < 0.f) m |= (1u << t);
        abits[i * 17 + jj] = m;
    }

    // ---- Stage write: linear LDS, coalesced ----
    ((uint4*)wlds)[2 * tid]     = w0;
    ((uint4*)wlds)[2 * tid + 1] = w1;
    ((float2*)plds)[tid]        = pp2;
    __syncthreads();

    // ---- Phase 2: bits from LDS; wbits/params from LDS (uniform broadcast
    //      ds_read -- the R6 change); residual x from global (L2-warm, same
    //      addresses phase 1 touched); plain stores (R1 lesson). ----
    uint32_t a[16];
    #pragma unroll
    for (int w = 0; w < 16; ++w) a[w] = abits[i * 17 + w];

    float* og = out + base;

    #pragma unroll
    for (int oo = 0; oo < 32; ++oo) {
        const int o = c0 + oo;                            // wave-uniform
        // 4x ds_read_b128 at wave-uniform addresses -> broadcast, no SMEM wait
        const uint4* wr4 = (const uint4*)(wlds + o * 16);
        const uint4 q0 = wr4[0], q1 = wr4[1], q2 = wr4[2], q3 = wr4[3];
        int P = 0;
        P += __popc(a[0]  ^ q0.x); P += __popc(a[1]  ^ q0.y);
        P += __popc(a[2]  ^ q0.z); P += __popc(a[3]  ^ q0.w);
        P += __popc(a[4]  ^ q1.x); P += __popc(a[5]  ^ q1.y);
        P += __popc(a[6]  ^ q1.z); P += __popc(a[7]  ^ q1.w);
        P += __popc(a[8]  ^ q2.x); P += __popc(a[9]  ^ q2.y);
        P += __popc(a[10] ^ q2.z); P += __popc(a[11] ^ q2.w);
        P += __popc(a[12] ^ q3.x); P += __popc(a[13] ^ q3.y);
        P += __popc(a[14] ^ q3.z); P += __popc(a[15] ^ q3.w);

        const float4 p = plds[o];                         // uniform ds_read
        const float t = fmaf(p.x, (float)P, p.y + xg[(size_t)o * HW_]);
        const float r = fmaf(p.z, fminf(t, 0.f), fmaxf(t, 0.f) + p.w);
        og[(size_t)o * HW_] = r;
    }
}

extern "C" void kernel_launch(void* const* d_in, const int* in_sizes, int n_in,
                              void* d_out, int out_size, void* d_ws, size_t ws_size,
                              hipStream_t stream) {
    const float* x          = (const float*)d_in[0];
    const float* rsign_bias = (const float*)d_in[1];
    const float* W          = (const float*)d_in[2];
    const float* bn_gamma   = (const float*)d_in[3];
    const float* bn_beta    = (const float*)d_in[4];
    const float* bn_mean    = (const float*)d_in[5];
    const float* bn_var     = (const float*)d_in[6];
    const float* pr_slope   = (const float*)d_in[7];
    const float* pr_shift   = (const float*)d_in[8];
    const float* pr_bias    = (const float*)d_in[9];
    float* out = (float*)d_out;

    uint32_t* wbits  = (uint32_t*)d_ws;
    float4*   params = (float4*)((char*)d_ws + 32768);

    precompute_kernel<<<dim3(C_), dim3(64), 0, stream>>>(
        W, bn_gamma, bn_beta, bn_mean, bn_var, pr_slope, pr_shift, pr_bias,
        wbits, params);

    // 50176 (b,hw) pairs = 784 tiles of 64, zero waste; 1024-thr blocks,
    // 2 blocks/CU.
    fused_kernel<<<dim3(784), dim3(64, 16), 0, stream>>>(
        x, rsign_bias, wbits, params, out);
}

// Round 7
// 243.140 us; speedup vs baseline: 1.1666x; 1.1666x over previous
//
#include <hip/hip_runtime.h>
#include <cstdint>

#define C_     512
#define HW_    784
#define B_     64
#define BN_EPS 1e-5f

// Workspace layout:
//   [0, 32768)     : wbits   uint32[512][16]  (bit c%32 of word c/32 = 1 iff W[o][c] < 0)
//   [32768, 40960) : params  float4[512]      {A2, C2, slope, bias}
//
// Math folding:
//   scale[o] = mean|W[o,:]| ; S = 512 - 2*P (P = popcount(a^wsign)) ; y = scale*S
//   bn = A*S + B2,  A = gamma*scale*r, B2 = beta - gamma*mean*r
//   t  = bn + x - shift = (-2A)*P + (512A + B2 - shift) + x = A2*P + C2 + x
//   out = max(t,0) + slope*min(t,0) + bias   (branchless RPReLU)
//
// Journal:
//   R1: nontemporal stores -> WRITE 100->238 MB + L3 eviction. Never again.
//   R2: xv[32] reg-cache defeated by remat under 64-VGPR cap. 83.3 us. BEST.
//   R3: sw-pipeline flattened by regalloc; L2 thrash. 113 us.
//   R4: asm-pin sank past the barrier with the loads; half occupancy. 97 us.
//   R5: split kernels: scheduler still caps MLP (~8); binarize +40 us. REVERTED.
//   R6: LDS-staging wbits/params (SMEM theory): DEAD. VALUBusy fell to 25,
//       staging thrashed L2/L3 (FETCH +121 MB, 200K bank conflicts). 137 us.
//   MODEL (R0-R6 synthesis): every variant moves ~296 MB combined logical
//       traffic at ~3.5 TB/s effective for this 256B-request/3136B-stride
//       pattern -> traffic-bound, not HBM- or SMEM-latency-bound. The only
//       controllable 1/3 of traffic is the phase-2 x re-read.
//   R7 (this): route the re-read through WAVE-PRIVATE LDS (xlds 128 KB,
//       lane-contiguous, 2-way alias = free). Compiler cannot remat it away.
//       Costs 1 block/CU (4 waves/SIMD) -- fine, phase 2 has zero global
//       reads. Otherwise byte-identical to R2.

__global__ __launch_bounds__(64) void precompute_kernel(
    const float* __restrict__ W,
    const float* __restrict__ bn_gamma, const float* __restrict__ bn_beta,
    const float* __restrict__ bn_mean,  const float* __restrict__ bn_var,
    const float* __restrict__ pr_slope, const float* __restrict__ pr_shift,
    const float* __restrict__ pr_bias,
    uint32_t* __restrict__ wbits, float4* __restrict__ params)
{
    const int o    = blockIdx.x;
    const int lane = threadIdx.x;
    const float4* wrow4 = (const float4*)(W + (size_t)o * C_);
    const float4 u = wrow4[2 * lane];
    const float4 v = wrow4[2 * lane + 1];

    float s = fabsf(u.x) + fabsf(u.y) + fabsf(u.z) + fabsf(u.w)
            + fabsf(v.x) + fabsf(v.y) + fabsf(v.z) + fabsf(v.w);
    for (int off = 32; off > 0; off >>= 1) s += __shfl_down(s, off, 64);

    uint32_t m8 = (u.x < 0.f ? 1u : 0u)  | (u.y < 0.f ? 2u : 0u)
                | (u.z < 0.f ? 4u : 0u)  | (u.w < 0.f ? 8u : 0u)
                | (v.x < 0.f ? 16u : 0u) | (v.y < 0.f ? 32u : 0u)
                | (v.z < 0.f ? 64u : 0u) | (v.w < 0.f ? 128u : 0u);

    const uint32_t g0 = __shfl(m8, 4 * lane + 0, 64);
    const uint32_t g1 = __shfl(m8, 4 * lane + 1, 64);
    const uint32_t g2 = __shfl(m8, 4 * lane + 2, 64);
    const uint32_t g3 = __shfl(m8, 4 * lane + 3, 64);
    if (lane < 16)
        wbits[o * 16 + lane] = g0 | (g1 << 8) | (g2 << 16) | (g3 << 24);

    if (lane == 0) {
        float scale = s * (1.0f / (float)C_);
        float r  = rsqrtf(bn_var[o] + BN_EPS);
        float A  = bn_gamma[o] * scale * r;
        float A2 = -2.0f * A;
        float C2 = (float)C_ * A + bn_beta[o] - bn_gamma[o] * bn_mean[o] * r
                 - pr_shift[o];
        params[o] = make_float4(A2, C2, pr_slope[o], pr_bias[o]);
    }
}

// Block: (64 lanes) x (16 waves) = 1024 threads; grid = 784 blocks covering
// the 50,176 flattened (b,hw) pairs exactly. Wave jj binarizes channels
// [32jj, 32jj+32) and computes outputs for those same channels.
// LDS: xlds 128 KB (wave-private x residual tile) + abits 4.4 KB = 132.4 KB
// -> 1 block/CU, 4 waves/SIMD. __launch_bounds__(1024,4): 128-VGPR budget.
// xlds layout [wave][ch][lane]: lane-contiguous -> bank = lane%32, 2-way
// alias on both ds_write and ds_read = free (m136).
__global__ __launch_bounds__(1024, 4) void fused_kernel(
    const float* __restrict__ x, const float* __restrict__ rsign_bias,
    const uint32_t* __restrict__ wbits, const float4* __restrict__ params,
    float* __restrict__ out)
{
    __shared__ uint32_t abits[64 * 17];      // stride 17: 2-way alias (free)
    __shared__ float    xlds[16][32][64];    // 128 KB wave-private x stage

    const int i  = threadIdx.x;                                   // pair lane
    const int jj = __builtin_amdgcn_readfirstlane(threadIdx.y);   // wave 0..15

    const uint32_t pair = (uint32_t)blockIdx.x * 64u + (uint32_t)i;
    const uint32_t b    = pair / 784u;          // magic-mul division
    const uint32_t hw   = pair - b * 784u;
    const size_t   base = (size_t)b * (C_ * HW_) + hw;
    const float*   xg   = x + base;

    const int c0 = jj * 32;                                       // wave-uniform

    // ---- Phase 1: load 32 channels once; stage residual to LDS + binarize ----
    {
        float v[32];
        #pragma unroll
        for (int t = 0; t < 32; ++t)
            v[t] = xg[(size_t)(c0 + t) * HW_];

        uint32_t m = 0;
        #pragma unroll
        for (int t = 0; t < 32; ++t) {
            xlds[jj][t][i] = v[t];                       // conflict-free
            if (v[t] + rsign_bias[c0 + t] < 0.f) m |= (1u << t);
        }
        abits[i * 17 + jj] = m;
    }
    __syncthreads();

    // ---- Phase 2: ZERO global reads. Bits from LDS, wbits/params via s_load
    //      (R2's proven path), residual x from wave-private LDS, plain stores. ----
    uint32_t a[16];
    #pragma unroll
    for (int w = 0; w < 16; ++w) a[w] = abits[i * 17 + w];

    float* og = out + base;

    #pragma unroll
    for (int oo = 0; oo < 32; ++oo) {
        const int o = c0 + oo;                           // wave-uniform
        const uint32_t* wr = wbits + o * 16;             // s_load rows
        int P = 0;
        #pragma unroll
        for (int w = 0; w < 16; ++w) P += __popc(a[w] ^ wr[w]);

        const float4 p = params[o];
        const float t = fmaf(p.x, (float)P, p.y + xlds[jj][oo][i]);
        const float r = fmaf(p.z, fminf(t, 0.f), fmaxf(t, 0.f) + p.w);
        og[(size_t)o * HW_] = r;
    }
}

extern "C" void kernel_launch(void* const* d_in, const int* in_sizes, int n_in,
                              void* d_out, int out_size, void* d_ws, size_t ws_size,
                              hipStream_t stream) {
    const float* x          = (const float*)d_in[0];
    const float* rsign_bias = (const float*)d_in[1];
    const float* W          = (const float*)d_in[2];
    const float* bn_gamma   = (const float*)d_in[3];
    const float* bn_beta    = (const float*)d_in[4];
    const float* bn_mean    = (const float*)d_in[5];
    const float* bn_var     = (const float*)d_in[6];
    const float* pr_slope   = (const float*)d_in[7];
    const float* pr_shift   = (const float*)d_in[8];
    const float* pr_bias    = (const float*)d_in[9];
    float* out = (float*)d_out;

    uint32_t* wbits  = (uint32_t*)d_ws;
    float4*   params = (float4*)((char*)d_ws + 32768);

    precompute_kernel<<<dim3(C_), dim3(64), 0, stream>>>(
        W, bn_gamma, bn_beta, bn_mean, bn_var, pr_slope, pr_shift, pr_bias,
        wbits, params);

    // 50176 (b,hw) pairs = 784 tiles of 64, zero waste; 1024-thr blocks,
    // 1 block/CU (LDS-capped; phase 2 needs no TLP -- zero global reads).
    fused_kernel<<<dim3(784), dim3(64, 16), 0, stream>>>(
        x, rsign_bias, wbits, params, out);
}